// Round 10
// baseline (10565.971 us; speedup 1.0000x reference)
//
#include <hip/hip_runtime.h>

constexpr int Ss = 128;          // S
constexpr int Hn = 1024;         // H
constexpr int En = 512;          // E
constexpr int Cn = 512;          // C
constexpr size_t PLF = 1024u * 1024u;

// Static fp32 scratch planes. Ping-pong h, y, z. Replay-safe:
// t=0 skips the h-GEMM and writes g_h[1]; g_h[0] first read at t=2 (written
// t=1); every g_y row written during the scan (len in [1,128]); g_z fully
// rewritten before read. No cross-launch state.
__device__ __align__(1024) float g_h[2][PLF];
__device__ __align__(1024) float g_y[PLF];
__device__ __align__(1024) float g_z[PLF];

// ---------------- RNN step, fp32 VALU ----------------
// h' = tanh(emb[x[b][t]] @ Wih^T + h @ Whh^T + bih + bhh)
// Tile: 64 batch rows x 64 j cols per block; 256 blocks; thread -> 4 rows x 2 cols.
__global__ void __launch_bounds__(512) step32(
    const int* __restrict__ x_in, const int* __restrict__ x_len,
    const float* __restrict__ emb, const float* __restrict__ Wih,
    const float* __restrict__ Whh, const float* __restrict__ bih,
    const float* __restrict__ bhh, int t)
{
  __shared__ float XT[32][68];   // X^T chunk [kk][row], padded
  __shared__ float WT[32][68];   // W^T chunk [kk][jj]
  __shared__ int   toks[64];
  __shared__ int   lens[64];

  const int tid = threadIdx.x, bid = blockIdx.x;
  const int b0 = (bid & 15) << 6, j0 = (bid >> 4) << 6;
  const int jc = (tid & 31) << 1;
  const int r0 = (tid >> 5) << 2;

  const float* hin = g_h[t & 1];
  float* hout = g_h[(t + 1) & 1];

  if (tid < 64) {
    toks[tid] = x_in[(b0 + tid) * Ss + t];
    lens[tid] = x_len[b0 + tid];
  }
  __syncthreads();

  float acc[4][2];
#pragma unroll
  for (int i = 0; i < 4; ++i) { acc[i][0] = 0.f; acc[i][1] = 0.f; }

  const int ei = tid * 4;
  const int srow = ei >> 5;        // 0..63
  const int kk0 = ei & 31;

  const int nkc = (t == 0) ? 16 : 48;   // t=0: h==0, emb chunks only
  for (int kc = 0; kc < nkc; ++kc) {
    const int kg = kc * 32 + kk0;
    float4 xv, wv;
    if (kg < En) {
      xv = *(const float4*)(emb + (size_t)toks[srow] * En + kg);
      wv = *(const float4*)(Wih + (size_t)(j0 + srow) * En + kg);
    } else {
      xv = *(const float4*)(hin + (size_t)(b0 + srow) * Hn + (kg - En));
      wv = *(const float4*)(Whh + (size_t)(j0 + srow) * Hn + (kg - En));
    }
    XT[kk0 + 0][srow] = xv.x; XT[kk0 + 1][srow] = xv.y;
    XT[kk0 + 2][srow] = xv.z; XT[kk0 + 3][srow] = xv.w;
    WT[kk0 + 0][srow] = wv.x; WT[kk0 + 1][srow] = wv.y;
    WT[kk0 + 2][srow] = wv.z; WT[kk0 + 3][srow] = wv.w;
    __syncthreads();
#pragma unroll
    for (int kk = 0; kk < 32; ++kk) {
      const float4 x4 = *(const float4*)&XT[kk][r0];
      const float2 w2 = *(const float2*)&WT[kk][jc];
      acc[0][0] += x4.x * w2.x; acc[0][1] += x4.x * w2.y;
      acc[1][0] += x4.y * w2.x; acc[1][1] += x4.y * w2.y;
      acc[2][0] += x4.z * w2.x; acc[2][1] += x4.z * w2.y;
      acc[3][0] += x4.w * w2.x; acc[3][1] += x4.w * w2.y;
    }
    __syncthreads();
  }

#pragma unroll
  for (int i = 0; i < 4; ++i) {
    const int row = b0 + r0 + i;
#pragma unroll
    for (int jj = 0; jj < 2; ++jj) {
      const int j = j0 + jc + jj;
      const float v = tanhf(acc[i][jj] + bih[j] + bhh[j]);
      hout[(size_t)row * Hn + j] = v;
      if (lens[r0 + i] == t + 1) g_y[(size_t)row * Hn + j] = v;
    }
  }
}

// ---------------- MLP layers, fp32 ----------------
// mode 0: g_z = relu(g_y @ W1^T + b1)       (grid 256)
// mode 1: out = g_z @ W2^T + b2  (FP32 out) (grid 128, j < 512)
__global__ void __launch_bounds__(512) mlp32(
    const float* __restrict__ W, const float* __restrict__ bias,
    float* __restrict__ out, int mode)
{
  __shared__ float XT[32][68];
  __shared__ float WT[32][68];

  const int tid = threadIdx.x, bid = blockIdx.x;
  const int b0 = (bid & 15) << 6, j0 = (bid >> 4) << 6;
  const int jc = (tid & 31) << 1;
  const int r0 = (tid >> 5) << 2;

  const float* src = (mode == 0) ? g_y : g_z;

  float acc[4][2];
#pragma unroll
  for (int i = 0; i < 4; ++i) { acc[i][0] = 0.f; acc[i][1] = 0.f; }

  const int ei = tid * 4;
  const int srow = ei >> 5;
  const int kk0 = ei & 31;

  for (int kc = 0; kc < 32; ++kc) {
    const int kg = kc * 32 + kk0;
    const float4 xv = *(const float4*)(src + (size_t)(b0 + srow) * Hn + kg);
    const float4 wv = *(const float4*)(W + (size_t)(j0 + srow) * Hn + kg);
    XT[kk0 + 0][srow] = xv.x; XT[kk0 + 1][srow] = xv.y;
    XT[kk0 + 2][srow] = xv.z; XT[kk0 + 3][srow] = xv.w;
    WT[kk0 + 0][srow] = wv.x; WT[kk0 + 1][srow] = wv.y;
    WT[kk0 + 2][srow] = wv.z; WT[kk0 + 3][srow] = wv.w;
    __syncthreads();
#pragma unroll
    for (int kk = 0; kk < 32; ++kk) {
      const float4 x4 = *(const float4*)&XT[kk][r0];
      const float2 w2 = *(const float2*)&WT[kk][jc];
      acc[0][0] += x4.x * w2.x; acc[0][1] += x4.x * w2.y;
      acc[1][0] += x4.y * w2.x; acc[1][1] += x4.y * w2.y;
      acc[2][0] += x4.z * w2.x; acc[2][1] += x4.z * w2.y;
      acc[3][0] += x4.w * w2.x; acc[3][1] += x4.w * w2.y;
    }
    __syncthreads();
  }

#pragma unroll
  for (int i = 0; i < 4; ++i) {
    const int row = b0 + r0 + i;
#pragma unroll
    for (int jj = 0; jj < 2; ++jj) {
      const int j = j0 + jc + jj;
      const float r = acc[i][jj] + bias[j];
      if (mode == 0) {
        g_z[(size_t)row * Hn + j] = fmaxf(r, 0.f);
      } else {
        out[(size_t)row * Cn + j] = r;       // FP32 output
      }
    }
  }
}

extern "C" void kernel_launch(void* const* d_in, const int* in_sizes, int n_in,
                              void* d_out, int out_size, void* d_ws, size_t ws_size,
                              hipStream_t stream) {
  const int*   x_in  = (const int*)d_in[0];
  const int*   x_len = (const int*)d_in[1];
  const float* emb = (const float*)d_in[2];
  const float* Wih = (const float*)d_in[3];
  const float* Whh = (const float*)d_in[4];
  const float* bih = (const float*)d_in[5];
  const float* bhh = (const float*)d_in[6];
  const float* W1  = (const float*)d_in[7];
  const float* b1  = (const float*)d_in[8];
  const float* W2  = (const float*)d_in[9];
  const float* b2  = (const float*)d_in[10];
  float* out = (float*)d_out;

  for (int t = 0; t < Ss; ++t)
    step32<<<dim3(256), dim3(512), 0, stream>>>(x_in, x_len, emb, Wih, Whh,
                                                bih, bhh, t);
  mlp32<<<dim3(256), dim3(512), 0, stream>>>(W1, b1, nullptr, 0);
  mlp32<<<dim3(128), dim3(512), 0, stream>>>(W2, b2, out, 1);
}

// Round 11
// 4974.853 us; speedup vs baseline: 2.1239x; 2.1239x over previous
//
#include <hip/hip_runtime.h>

typedef unsigned short u16;
constexpr int Ss = 128, Hn = 1024, En = 512, Cn = 512, Vn = 32000;
constexpr size_t PL = 1024u * 1024u;

using short8 = __attribute__((ext_vector_type(8))) short;
using f32x4  = __attribute__((ext_vector_type(4))) float;

// ---- static device scratch (all planes rewritten in-launch before read) ----
__device__ __align__(1024) u16 g_hh[2][PL];   // h ping-pong, hi
__device__ __align__(1024) u16 g_hl[2][PL];   // h ping-pong, lo
__device__ __align__(1024) u16 g_yh[PL], g_yl[PL];
__device__ __align__(1024) u16 g_zh[PL], g_zl[PL];
__device__ __align__(1024) float g_xp[(size_t)131072 * 1024];  // [b][t][j] fp32, bias folded
// bf16 hi/lo split tables (recomputed every launch; deterministic)
__device__ __align__(1024) u16 t_eh[(size_t)Vn * En], t_el[(size_t)Vn * En];
__device__ __align__(1024) u16 t_xh[(size_t)Hn * En], t_xl[(size_t)Hn * En];  // Wih
__device__ __align__(1024) u16 t_hh[(size_t)Hn * Hn], t_hl[(size_t)Hn * Hn];  // Whh
__device__ __align__(1024) u16 t_1h[(size_t)Hn * Hn], t_1l[(size_t)Hn * Hn];  // W1
__device__ __align__(1024) u16 t_2h[(size_t)Cn * Hn], t_2l[(size_t)Cn * Hn];  // W2

__device__ __forceinline__ void gl16(const void* g, void* l) {
  __builtin_amdgcn_global_load_lds((const __attribute__((address_space(1))) void*)g,
                                   (__attribute__((address_space(3))) void*)l, 16, 0, 0);
}
__device__ __forceinline__ unsigned f2bf(float f) {
  unsigned u = __float_as_uint(f);
  return (u + 0x7fffu + ((u >> 16) & 1u)) >> 16;
}
__device__ __forceinline__ float bf2f(unsigned u) { return __uint_as_float(u << 16); }

// fp32 -> (hi, lo) bf16 split tables
__global__ void cvt_split(const float* __restrict__ src, int which, int n) {
  u16 *hi, *lo;
  switch (which) {
    case 0: hi = t_eh; lo = t_el; break;
    case 1: hi = t_xh; lo = t_xl; break;
    case 2: hi = t_hh; lo = t_hl; break;
    case 3: hi = t_1h; lo = t_1l; break;
    default: hi = t_2h; lo = t_2l; break;
  }
  for (int i = blockIdx.x * blockDim.x + threadIdx.x; i < n; i += gridDim.x * blockDim.x) {
    const float v = src[i];
    const unsigned h = f2bf(v);
    hi[i] = (u16)h;
    lo[i] = (u16)f2bf(v - bf2f(h));
  }
}

// Shared GEMM-tile index prolog (64x64 tile, 8 waves 4x2, m89-verified frags,
// XOR-swizzled LDS staged via gl16 — machinery bit-validated r3==r4).
#define GEMM_PROLOG()                                                          \
  const int tid = threadIdx.x, bid = blockIdx.x;                               \
  const int w = tid >> 6, l = tid & 63;                                        \
  const int wr = w & 3, wc = w >> 2;                                           \
  const int lrow = l & 15, lk = l >> 4;                                        \
  const int sr = tid >> 3, p = tid & 7;                                        \
  const int sby = ((p ^ (sr & 7)) << 4);                                       \
  const int arow = (wr << 4) + lrow;                                           \
  int aoff[2], bboff[2][2];                                                    \
  _Pragma("unroll") for (int s = 0; s < 2; ++s)                                \
      aoff[s] = arow * 128 + ((s * 64 + lk * 16) ^ ((arow & 7) << 4));         \
  _Pragma("unroll") for (int n = 0; n < 2; ++n) {                              \
    const int jl = (wc << 5) + (n << 4) + lrow;                                \
    _Pragma("unroll") for (int s = 0; s < 2; ++s)                              \
        bboff[n][s] = jl * 128 + ((s * 64 + lk * 16) ^ ((jl & 7) << 4));       \
  }

#define GEMM_MFMA(ca, cb)                                                      \
  _Pragma("unroll") for (int s = 0; s < 2; ++s) {                              \
    short8 a = *(const short8*)((ca) + aoff[s]);                               \
    _Pragma("unroll") for (int n = 0; n < 2; ++n) {                            \
      short8 b = *(const short8*)((cb) + bboff[n][s]);                         \
      acc[n] = __builtin_amdgcn_mfma_f32_16x16x32_bf16(a, b, acc[n], 0, 0, 0); \
    }                                                                          \
  }

// xproj[b][t][j] = emb[tok(b,t)] @ Wih^T + bih + bhh   (3-product split, K=1536)
__global__ void __launch_bounds__(512) xproj_k(const int* __restrict__ x_in,
                                               const float* __restrict__ bih,
                                               const float* __restrict__ bhh) {
  __shared__ char sA[16384];
  __shared__ char sB[16384];
  __shared__ int toks[64];
  GEMM_PROLOG()
  const int j0 = (bid & 15) << 6;
  const int m0 = (bid >> 4) << 6;        // 64 consecutive m = b*128+t (same b)
  const int bat = m0 >> 7, t0 = m0 & 127;
  if (tid < 64) toks[tid] = x_in[bat * Ss + t0 + tid];
  __syncthreads();
  const int myTok = toks[sr];

  f32x4 acc[2];
#pragma unroll
  for (int n = 0; n < 2; ++n) {
    const float bs = bih[j0 + (wc << 5) + (n << 4) + lrow] +
                     bhh[j0 + (wc << 5) + (n << 4) + lrow];
#pragma unroll
    for (int ri = 0; ri < 4; ++ri) acc[n][ri] = bs;
  }

  // A = [e_hi(0-7) | e_lo(8-15) | e_hi(16-23)], B = [Wih_hi | Wih_hi | Wih_lo]
  auto stage = [&](int c) {
    char* da = sA + (c & 1) * 8192;
    char* db = sB + (c & 1) * 8192;
    const u16* ap = (c >= 8 && c < 16) ? t_el : t_eh;
    const u16* bp = (c < 16) ? t_xh : t_xl;
    const int kb = (c & 7) * 128;
    gl16((const char*)ap + (size_t)myTok * 1024 + kb + sby, da + w * 1024);
    gl16((const char*)bp + (size_t)(j0 + sr) * 1024 + kb + sby, db + w * 1024);
  };
  stage(0);
  __syncthreads();
  for (int c = 0; c < 24; ++c) {
    const char* ca = sA + (c & 1) * 8192;
    const char* cb = sB + (c & 1) * 8192;
    if (c < 23) stage(c + 1);
    GEMM_MFMA(ca, cb)
    __syncthreads();
  }
#pragma unroll
  for (int n = 0; n < 2; ++n) {
    const int j = j0 + (wc << 5) + (n << 4) + lrow;
#pragma unroll
    for (int ri = 0; ri < 4; ++ri) {
      const int m = m0 + (wr << 4) + lk * 4 + ri;
      g_xp[(size_t)m * 1024 + j] = acc[n][ri];
    }
  }
}

// one RNN step: h' = tanh(xproj + (h_hi+h_lo)@Whh_hi + h_hi@Whh_lo)  (K=3072)
__global__ void __launch_bounds__(512) step_k(const int* __restrict__ x_len, int t) {
  __shared__ char sA[16384];
  __shared__ char sB[16384];
  GEMM_PROLOG()
  const int b0 = (bid & 15) << 6, j0 = (bid >> 4) << 6;
  const u16* hinh = g_hh[t & 1];
  const u16* hinl = g_hl[t & 1];
  u16* houth = g_hh[(t + 1) & 1];
  u16* houtl = g_hl[(t + 1) & 1];

  f32x4 acc[2];
#pragma unroll
  for (int n = 0; n < 2; ++n) {
    const int j = j0 + (wc << 5) + (n << 4) + lrow;
#pragma unroll
    for (int ri = 0; ri < 4; ++ri) {
      const int brow = b0 + (wr << 4) + lk * 4 + ri;
      acc[n][ri] = g_xp[((size_t)brow * 128 + t) * 1024 + j];  // fp32 C-init
    }
  }

  if (t > 0) {
    // A = [h_hi(0-15) | h_lo(16-31) | h_hi(32-47)], B = [Whi | Whi | Wlo]
    auto stage = [&](int c) {
      char* da = sA + (c & 1) * 8192;
      char* db = sB + (c & 1) * 8192;
      const u16* ap = (c >= 16 && c < 32) ? hinl : hinh;
      const u16* bp = (c < 32) ? t_hh : t_hl;
      const int kb = (c & 15) * 128;
      gl16((const char*)ap + (size_t)(b0 + sr) * 2048 + kb + sby, da + w * 1024);
      gl16((const char*)bp + (size_t)(j0 + sr) * 2048 + kb + sby, db + w * 1024);
    };
    stage(0);
    __syncthreads();
    for (int c = 0; c < 48; ++c) {
      const char* ca = sA + (c & 1) * 8192;
      const char* cb = sB + (c & 1) * 8192;
      if (c < 47) stage(c + 1);
      GEMM_MFMA(ca, cb)
      __syncthreads();
    }
  }

#pragma unroll
  for (int n = 0; n < 2; ++n) {
    const int j = j0 + (wc << 5) + (n << 4) + lrow;
#pragma unroll
    for (int ri = 0; ri < 4; ++ri) {
      const int brow = b0 + (wr << 4) + lk * 4 + ri;
      const float v = tanhf(acc[n][ri]);
      const unsigned hi = f2bf(v);
      const unsigned lo = f2bf(v - bf2f(hi));
      const size_t off = (size_t)brow * 1024 + j;
      houth[off] = (u16)hi;
      houtl[off] = (u16)lo;
      if (x_len[brow] == t + 1) { g_yh[off] = (u16)hi; g_yl[off] = (u16)lo; }
    }
  }
}

// MLP: mode 0: z = relu(y@W1^T + b1) split-stored; mode 1: out = z@W2^T + b2 fp32
__global__ void __launch_bounds__(512) mlp_k(const float* __restrict__ bias,
                                             float* __restrict__ out, int mode) {
  __shared__ char sA[16384];
  __shared__ char sB[16384];
  GEMM_PROLOG()
  const int b0 = (bid & 15) << 6, j0 = (bid >> 4) << 6;
  const u16* ah = mode ? g_zh : g_yh;
  const u16* al = mode ? g_zl : g_yl;
  const u16* bh = mode ? t_2h : t_1h;
  const u16* bl = mode ? t_2l : t_1l;

  f32x4 acc[2];
#pragma unroll
  for (int n = 0; n < 2; ++n) {
    const float bs = bias[j0 + (wc << 5) + (n << 4) + lrow];
#pragma unroll
    for (int ri = 0; ri < 4; ++ri) acc[n][ri] = bs;
  }

  auto stage = [&](int c) {
    char* da = sA + (c & 1) * 8192;
    char* db = sB + (c & 1) * 8192;
    const u16* ap = (c >= 16 && c < 32) ? al : ah;
    const u16* bp = (c < 32) ? bh : bl;
    const int kb = (c & 15) * 128;
    gl16((const char*)ap + (size_t)(b0 + sr) * 2048 + kb + sby, da + w * 1024);
    gl16((const char*)bp + (size_t)(j0 + sr) * 2048 + kb + sby, db + w * 1024);
  };
  stage(0);
  __syncthreads();
  for (int c = 0; c < 48; ++c) {
    const char* ca = sA + (c & 1) * 8192;
    const char* cb = sB + (c & 1) * 8192;
    if (c < 47) stage(c + 1);
    GEMM_MFMA(ca, cb)
    __syncthreads();
  }

#pragma unroll
  for (int n = 0; n < 2; ++n) {
    const int j = j0 + (wc << 5) + (n << 4) + lrow;
#pragma unroll
    for (int ri = 0; ri < 4; ++ri) {
      const int brow = b0 + (wr << 4) + lk * 4 + ri;
      if (mode == 0) {
        const float v = fmaxf(acc[n][ri], 0.f);
        const unsigned hi = f2bf(v);
        const unsigned lo = f2bf(v - bf2f(hi));
        const size_t off = (size_t)brow * 1024 + j;
        g_zh[off] = (u16)hi;
        g_zl[off] = (u16)lo;
      } else {
        out[(size_t)brow * 512 + j] = acc[n][ri];
      }
    }
  }
}

extern "C" void kernel_launch(void* const* d_in, const int* in_sizes, int n_in,
                              void* d_out, int out_size, void* d_ws, size_t ws_size,
                              hipStream_t stream) {
  const int*   x_in  = (const int*)d_in[0];
  const int*   x_len = (const int*)d_in[1];
  const float* emb = (const float*)d_in[2];
  const float* Wih = (const float*)d_in[3];
  const float* Whh = (const float*)d_in[4];
  const float* bih = (const float*)d_in[5];
  const float* bhh = (const float*)d_in[6];
  const float* W1  = (const float*)d_in[7];
  const float* b1  = (const float*)d_in[8];
  const float* W2  = (const float*)d_in[9];
  const float* b2  = (const float*)d_in[10];
  float* out = (float*)d_out;

  cvt_split<<<dim3(4096), dim3(256), 0, stream>>>(emb, 0, Vn * En);
  cvt_split<<<dim3(1024), dim3(256), 0, stream>>>(Wih, 1, Hn * En);
  cvt_split<<<dim3(2048), dim3(256), 0, stream>>>(Whh, 2, Hn * Hn);
  cvt_split<<<dim3(2048), dim3(256), 0, stream>>>(W1, 3, Hn * Hn);
  cvt_split<<<dim3(1024), dim3(256), 0, stream>>>(W2, 4, Cn * Hn);

  xproj_k<<<dim3(32768), dim3(512), 0, stream>>>(x_in, bih, bhh);

  for (int t = 0; t < Ss; ++t)
    step_k<<<dim3(256), dim3(512), 0, stream>>>(x_len, t);

  mlp_k<<<dim3(256), dim3(512), 0, stream>>>(b1, nullptr, 0);
  mlp_k<<<dim3(128), dim3(512), 0, stream>>>(b2, out, 1);
}

// Round 12
// 4232.795 us; speedup vs baseline: 2.4962x; 1.1753x over previous
//
#include <hip/hip_runtime.h>

typedef unsigned short u16;
constexpr int Ss = 128, Hn = 1024, En = 512, Cn = 512, Vn = 32000;
constexpr size_t PL = 1024u * 1024u;

using short8 = __attribute__((ext_vector_type(8))) short;
using f32x4  = __attribute__((ext_vector_type(4))) float;

// ---- static device scratch (all planes rewritten in-launch before read) ----
__device__ __align__(1024) u16 g_hh[2][PL];   // h ping-pong, hi
__device__ __align__(1024) u16 g_hl[2][PL];   // h ping-pong, lo
__device__ __align__(1024) u16 g_yh[PL], g_yl[PL];
__device__ __align__(1024) u16 g_zh[PL], g_zl[PL];
__device__ __align__(1024) float g_proj[(size_t)Vn * Hn];  // emb@Wih^T + bih + bhh
// bf16 hi/lo split tables (recomputed every launch; deterministic)
__device__ __align__(1024) u16 t_eh[(size_t)Vn * En], t_el[(size_t)Vn * En];
__device__ __align__(1024) u16 t_xh[(size_t)Hn * En], t_xl[(size_t)Hn * En];  // Wih
__device__ __align__(1024) u16 t_hh[(size_t)Hn * Hn], t_hl[(size_t)Hn * Hn];  // Whh
__device__ __align__(1024) u16 t_1h[(size_t)Hn * Hn], t_1l[(size_t)Hn * Hn];  // W1
__device__ __align__(1024) u16 t_2h[(size_t)Cn * Hn], t_2l[(size_t)Cn * Hn];  // W2

__device__ __forceinline__ void gl16(const void* g, void* l) {
  __builtin_amdgcn_global_load_lds((const __attribute__((address_space(1))) void*)g,
                                   (__attribute__((address_space(3))) void*)l, 16, 0, 0);
}
__device__ __forceinline__ unsigned f2bf(float f) {
  unsigned u = __float_as_uint(f);
  return (u + 0x7fffu + ((u >> 16) & 1u)) >> 16;
}
__device__ __forceinline__ float bf2f(unsigned u) { return __uint_as_float(u << 16); }

__global__ void cvt_split(const float* __restrict__ src, int which, int n) {
  u16 *hi, *lo;
  switch (which) {
    case 0: hi = t_eh; lo = t_el; break;
    case 1: hi = t_xh; lo = t_xl; break;
    case 2: hi = t_hh; lo = t_hl; break;
    case 3: hi = t_1h; lo = t_1l; break;
    default: hi = t_2h; lo = t_2l; break;
  }
  for (int i = blockIdx.x * blockDim.x + threadIdx.x; i < n; i += gridDim.x * blockDim.x) {
    const float v = src[i];
    const unsigned h = f2bf(v);
    hi[i] = (u16)h;
    lo[i] = (u16)f2bf(v - bf2f(h));
  }
}

// Shared GEMM-tile prolog (64x64 tile, 8 waves 4x2, m89-verified frags,
// XOR-swizzled LDS via gl16 — machinery validated r3==r4, green r11).
#define GEMM_PROLOG()                                                          \
  const int tid = threadIdx.x, bid = blockIdx.x;                               \
  const int w = tid >> 6, l = tid & 63;                                        \
  const int wr = w & 3, wc = w >> 2;                                           \
  const int lrow = l & 15, lk = l >> 4;                                        \
  const int sr = tid >> 3, p = tid & 7;                                        \
  const int sby = ((p ^ (sr & 7)) << 4);                                       \
  const int arow = (wr << 4) + lrow;                                           \
  int aoff[2], bboff[2][2];                                                    \
  _Pragma("unroll") for (int s = 0; s < 2; ++s)                                \
      aoff[s] = arow * 128 + ((s * 64 + lk * 16) ^ ((arow & 7) << 4));         \
  _Pragma("unroll") for (int n = 0; n < 2; ++n) {                              \
    const int jl = (wc << 5) + (n << 4) + lrow;                                \
    _Pragma("unroll") for (int s = 0; s < 2; ++s)                              \
        bboff[n][s] = jl * 128 + ((s * 64 + lk * 16) ^ ((jl & 7) << 4));       \
  }

#define GEMM_MFMA(ca, cb)                                                      \
  _Pragma("unroll") for (int s = 0; s < 2; ++s) {                              \
    short8 a = *(const short8*)((ca) + aoff[s]);                               \
    _Pragma("unroll") for (int n = 0; n < 2; ++n) {                            \
      short8 b = *(const short8*)((cb) + bboff[n][s]);                         \
      acc[n] = __builtin_amdgcn_mfma_f32_16x16x32_bf16(a, b, acc[n], 0, 0, 0); \
    }                                                                          \
  }

// proj[v][j] = emb[v] @ Wih^T + bih[j] + bhh[j]   (3-product split, K=1536)
__global__ void __launch_bounds__(512) proj_k(const float* __restrict__ bih,
                                              const float* __restrict__ bhh) {
  __shared__ char sA[16384];
  __shared__ char sB[16384];
  GEMM_PROLOG()
  const int j0 = (bid & 15) << 6;
  const int v0 = (bid >> 4) << 6;

  f32x4 acc[2];
#pragma unroll
  for (int n = 0; n < 2; ++n) {
    const float bs = bih[j0 + (wc << 5) + (n << 4) + lrow] +
                     bhh[j0 + (wc << 5) + (n << 4) + lrow];
#pragma unroll
    for (int ri = 0; ri < 4; ++ri) acc[n][ri] = bs;
  }

  // A = [e_hi(0-7) | e_lo(8-15) | e_hi(16-23)], B = [Wih_hi | Wih_hi | Wih_lo]
  auto stage = [&](int c) {
    char* da = sA + (c & 1) * 8192;
    char* db = sB + (c & 1) * 8192;
    const u16* ap = (c >= 8 && c < 16) ? t_el : t_eh;
    const u16* bp = (c < 16) ? t_xh : t_xl;
    const int kb = (c & 7) * 128;
    gl16((const char*)ap + (size_t)(v0 + sr) * 1024 + kb + sby, da + w * 1024);
    gl16((const char*)bp + (size_t)(j0 + sr) * 1024 + kb + sby, db + w * 1024);
  };
  stage(0);
  __syncthreads();
  for (int c = 0; c < 24; ++c) {
    const char* ca = sA + (c & 1) * 8192;
    const char* cb = sB + (c & 1) * 8192;
    if (c < 23) stage(c + 1);
    GEMM_MFMA(ca, cb)
    __syncthreads();
  }
#pragma unroll
  for (int n = 0; n < 2; ++n) {
    const int j = j0 + (wc << 5) + (n << 4) + lrow;
#pragma unroll
    for (int ri = 0; ri < 4; ++ri)
      g_proj[(size_t)(v0 + (wr << 4) + lk * 4 + ri) * 1024 + j] = acc[n][ri];
  }
}

// one RNN step: h' = tanh(proj[tok] + (h_hi+h_lo)@Whh_hi + h_hi@Whh_lo), K=3072.
// K-loop: 4-deep ring, counted vmcnt (T4), raw barriers — never vmcnt(0) mid-loop.
__global__ void __launch_bounds__(512) step_k(const int* __restrict__ x_in,
                                              const int* __restrict__ x_len, int t) {
  __shared__ char sA[32768];   // 4-slot ring
  __shared__ char sB[32768];
  __shared__ int toks[64];
  GEMM_PROLOG()
  const int b0 = (bid & 15) << 6, j0 = (bid >> 4) << 6;
  const u16* hinh = g_hh[t & 1];
  const u16* hinl = g_hl[t & 1];
  u16* houth = g_hh[(t + 1) & 1];
  u16* houtl = g_hl[(t + 1) & 1];

  if (tid < 64) toks[tid] = x_in[(b0 + tid) * Ss + t];
  __syncthreads();

  // x-projection gather (consumed in the tail -> off the K-loop critical path)
  float pj[2][4];
#pragma unroll
  for (int n = 0; n < 2; ++n) {
    const int j = j0 + (wc << 5) + (n << 4) + lrow;
#pragma unroll
    for (int ri = 0; ri < 4; ++ri)
      pj[n][ri] = g_proj[(size_t)toks[(wr << 4) + lk * 4 + ri] * 1024 + j];
  }

  f32x4 acc[2];
  acc[0] = (f32x4){0.f, 0.f, 0.f, 0.f}; acc[1] = acc[0];

  if (t > 0) {
    // A = [h_hi(0-15) | h_lo(16-31) | h_hi(32-47)], B = [Whi | Whi | Wlo]
    auto stage = [&](int c) {
      char* da = sA + (c & 3) * 8192;
      char* db = sB + (c & 3) * 8192;
      const u16* ap = (c >= 16 && c < 32) ? hinl : hinh;
      const u16* bp = (c < 32) ? t_hh : t_hl;
      const int kb = (c & 15) * 128;
      gl16((const char*)ap + (size_t)(b0 + sr) * 2048 + kb + sby, da + w * 1024);
      gl16((const char*)bp + (size_t)(j0 + sr) * 2048 + kb + sby, db + w * 1024);
    };
    stage(0); stage(1); stage(2);
    for (int c = 0; c < 48; ++c) {
      if (c + 3 < 48) stage(c + 3);
      const int ahead = (47 - c) < 3 ? (47 - c) : 3;  // stages still in flight
      if (ahead == 3)      asm volatile("s_waitcnt vmcnt(6)" ::: "memory");
      else if (ahead == 2) asm volatile("s_waitcnt vmcnt(4)" ::: "memory");
      else if (ahead == 1) asm volatile("s_waitcnt vmcnt(2)" ::: "memory");
      else                 asm volatile("s_waitcnt vmcnt(0)" ::: "memory");
      __builtin_amdgcn_s_barrier();          // all waves' stage(c) writes visible
      __builtin_amdgcn_sched_barrier(0);     // rule #18: no LDS-read hoisting
      const char* ca = sA + (c & 3) * 8192;
      const char* cb = sB + (c & 3) * 8192;
      GEMM_MFMA(ca, cb)
      __builtin_amdgcn_s_barrier();          // done reading slot before overwrite
    }
  }

#pragma unroll
  for (int n = 0; n < 2; ++n) {
    const int j = j0 + (wc << 5) + (n << 4) + lrow;
#pragma unroll
    for (int ri = 0; ri < 4; ++ri) {
      const int brow = b0 + (wr << 4) + lk * 4 + ri;
      const float v = tanhf(acc[n][ri] + pj[n][ri]);
      const unsigned hi = f2bf(v);
      const unsigned lo = f2bf(v - bf2f(hi));
      const size_t off = (size_t)brow * 1024 + j;
      houth[off] = (u16)hi;
      houtl[off] = (u16)lo;
      if (x_len[brow] == t + 1) { g_yh[off] = (u16)hi; g_yl[off] = (u16)lo; }
    }
  }
}

// MLP: mode 0: z = relu(y@W1^T + b1) split-stored; mode 1: out = z@W2^T + b2 fp32
__global__ void __launch_bounds__(512) mlp_k(const float* __restrict__ bias,
                                             float* __restrict__ out, int mode) {
  __shared__ char sA[16384];
  __shared__ char sB[16384];
  GEMM_PROLOG()
  const int b0 = (bid & 15) << 6, j0 = (bid >> 4) << 6;
  const u16* ah = mode ? g_zh : g_yh;
  const u16* al = mode ? g_zl : g_yl;
  const u16* bh = mode ? t_2h : t_1h;
  const u16* bl = mode ? t_2l : t_1l;

  f32x4 acc[2];
#pragma unroll
  for (int n = 0; n < 2; ++n) {
    const float bs = bias[j0 + (wc << 5) + (n << 4) + lrow];
#pragma unroll
    for (int ri = 0; ri < 4; ++ri) acc[n][ri] = bs;
  }

  auto stage = [&](int c) {
    char* da = sA + (c & 1) * 8192;
    char* db = sB + (c & 1) * 8192;
    const u16* ap = (c >= 16 && c < 32) ? al : ah;
    const u16* bp = (c < 32) ? bh : bl;
    const int kb = (c & 15) * 128;
    gl16((const char*)ap + (size_t)(b0 + sr) * 2048 + kb + sby, da + w * 1024);
    gl16((const char*)bp + (size_t)(j0 + sr) * 2048 + kb + sby, db + w * 1024);
  };
  stage(0);
  __syncthreads();
  for (int c = 0; c < 48; ++c) {
    const char* ca = sA + (c & 1) * 8192;
    const char* cb = sB + (c & 1) * 8192;
    if (c < 47) stage(c + 1);
    GEMM_MFMA(ca, cb)
    __syncthreads();
  }

#pragma unroll
  for (int n = 0; n < 2; ++n) {
    const int j = j0 + (wc << 5) + (n << 4) + lrow;
#pragma unroll
    for (int ri = 0; ri < 4; ++ri) {
      const int brow = b0 + (wr << 4) + lk * 4 + ri;
      if (mode == 0) {
        const float v = fmaxf(acc[n][ri], 0.f);
        const unsigned hi = f2bf(v);
        const unsigned lo = f2bf(v - bf2f(hi));
        const size_t off = (size_t)brow * 1024 + j;
        g_zh[off] = (u16)hi;
        g_zl[off] = (u16)lo;
      } else {
        out[(size_t)brow * 512 + j] = acc[n][ri];
      }
    }
  }
}

extern "C" void kernel_launch(void* const* d_in, const int* in_sizes, int n_in,
                              void* d_out, int out_size, void* d_ws, size_t ws_size,
                              hipStream_t stream) {
  const int*   x_in  = (const int*)d_in[0];
  const int*   x_len = (const int*)d_in[1];
  const float* emb = (const float*)d_in[2];
  const float* Wih = (const float*)d_in[3];
  const float* Whh = (const float*)d_in[4];
  const float* bih = (const float*)d_in[5];
  const float* bhh = (const float*)d_in[6];
  const float* W1  = (const float*)d_in[7];
  const float* b1  = (const float*)d_in[8];
  const float* W2  = (const float*)d_in[9];
  const float* b2  = (const float*)d_in[10];
  float* out = (float*)d_out;

  cvt_split<<<dim3(4096), dim3(256), 0, stream>>>(emb, 0, Vn * En);
  cvt_split<<<dim3(1024), dim3(256), 0, stream>>>(Wih, 1, Hn * En);
  cvt_split<<<dim3(2048), dim3(256), 0, stream>>>(Whh, 2, Hn * Hn);
  cvt_split<<<dim3(2048), dim3(256), 0, stream>>>(W1, 3, Hn * Hn);
  cvt_split<<<dim3(1024), dim3(256), 0, stream>>>(W2, 4, Cn * Hn);

  proj_k<<<dim3(8000), dim3(512), 0, stream>>>(bih, bhh);

  for (int t = 0; t < Ss; ++t)
    step_k<<<dim3(256), dim3(512), 0, stream>>>(x_in, x_len, t);

  mlp_k<<<dim3(256), dim3(512), 0, stream>>>(b1, nullptr, 0);
  mlp_k<<<dim3(128), dim3(512), 0, stream>>>(b2, out, 1);
}